// Round 1
// baseline (452.049 us; speedup 1.0000x reference)
//
#include <hip/hip_runtime.h>
#include <hip/hip_bf16.h>
#include <math.h>

#define NEG (-1.0e9f)

typedef __bf16 bf16_t;
typedef __bf16 bf16x8 __attribute__((ext_vector_type(8)));
typedef float f32x4 __attribute__((ext_vector_type(4)));

#define SS 64
#define BB 8
#define HH 512
#define VV 8192
#define NPAIR 1953          /* upper-tri pairs (i<j) over [0,63) */
#define NPTOT 1954          /* + (0,0) row for init_lp */
#define MROWS (NPTOT*BB)    /* 15632 */
#define MPAD  15744         /* 123*128 */

__device__ __forceinline__ float logsig(float x) { return -logf(1.0f + expf(-x)); }

__global__ void k_zero(float* p, int n) {
  int i = blockIdx.x * blockDim.x + threadIdx.x;
  if (i < n) p[i] = 0.0f;
}

__global__ void k_cvt(const float* __restrict__ in, bf16_t* __restrict__ out, int n) {
  int i = blockIdx.x * blockDim.x + threadIdx.x;
  if (i < n) out[i] = (bf16_t)in[i];
}

// transpose fp32 (R x C) -> bf16 (C x R)
__global__ __launch_bounds__(256) void k_tcvt(const float* __restrict__ in, bf16_t* __restrict__ out,
                                              int R, int C) {
  __shared__ float tile[32][33];
  int c0 = blockIdx.x * 32, r0 = blockIdx.y * 32;
  int tx = threadIdx.x & 31, ty = threadIdx.x >> 5;
  for (int i = ty; i < 32; i += 8)
    tile[i][tx] = in[(size_t)(r0 + i) * C + c0 + tx];
  __syncthreads();
  for (int i = ty; i < 32; i += 8)
    out[(size_t)(c0 + i) * R + r0 + tx] = (bf16_t)tile[tx][i];
}

// C = A(MxK) @ BT(NxK)^T.  MODE 0: store fp32 C. MODE 1: sumexp[row] += sum_col exp(C+bias)
template<int MODE>
__global__ __launch_bounds__(256) void k_gemm(
    const bf16_t* __restrict__ A, int lda,
    const bf16_t* __restrict__ BT, int ldb,
    float* __restrict__ Cout, int ldc,
    const float* __restrict__ bias,
    float* __restrict__ sumexp,
    int K)
{
  __shared__ __align__(16) bf16_t As[128 * 32];
  __shared__ __align__(16) bf16_t Bs[128 * 32];
  const int tid = threadIdx.x;
  const int lane = tid & 63;
  const int wave = tid >> 6;
  const int wr = wave >> 1, wc = wave & 1;
  const int m0 = blockIdx.x * 128, n0 = blockIdx.y * 128;

  const int rowS = tid >> 2;          // 0..63
  const int kS = (tid & 3) * 8;
  const bf16_t* gA0 = A + (size_t)(m0 + rowS) * lda + kS;
  const bf16_t* gA1 = A + (size_t)(m0 + rowS + 64) * lda + kS;
  const bf16_t* gB0 = BT + (size_t)(n0 + rowS) * ldb + kS;
  const bf16_t* gB1 = BT + (size_t)(n0 + rowS + 64) * ldb + kS;

  f32x4 acc[4][4] = {};

  const int aoff = (wr * 64 + (lane & 15)) * 32 + (lane >> 4) * 8;
  const int boff = (wc * 64 + (lane & 15)) * 32 + (lane >> 4) * 8;

  for (int k0 = 0; k0 < K; k0 += 32) {
    __builtin_amdgcn_global_load_lds((const __attribute__((address_space(1))) void*)(gA0 + k0),
        (__attribute__((address_space(3))) void*)(As + wave * 512), 16, 0, 0);
    __builtin_amdgcn_global_load_lds((const __attribute__((address_space(1))) void*)(gA1 + k0),
        (__attribute__((address_space(3))) void*)(As + 2048 + wave * 512), 16, 0, 0);
    __builtin_amdgcn_global_load_lds((const __attribute__((address_space(1))) void*)(gB0 + k0),
        (__attribute__((address_space(3))) void*)(Bs + wave * 512), 16, 0, 0);
    __builtin_amdgcn_global_load_lds((const __attribute__((address_space(1))) void*)(gB1 + k0),
        (__attribute__((address_space(3))) void*)(Bs + 2048 + wave * 512), 16, 0, 0);
    __syncthreads();

    bf16x8 af[4], bfr[4];
    #pragma unroll
    for (int mf = 0; mf < 4; ++mf)
      af[mf] = *(const bf16x8*)&As[aoff + mf * 16 * 32];
    #pragma unroll
    for (int nf = 0; nf < 4; ++nf)
      bfr[nf] = *(const bf16x8*)&Bs[boff + nf * 16 * 32];
    #pragma unroll
    for (int mf = 0; mf < 4; ++mf)
      #pragma unroll
      for (int nf = 0; nf < 4; ++nf)
        acc[mf][nf] = __builtin_amdgcn_mfma_f32_16x16x32_bf16(af[mf], bfr[nf], acc[mf][nf], 0, 0, 0);
    __syncthreads();
  }

  if (MODE == 0) {
    #pragma unroll
    for (int mf = 0; mf < 4; ++mf) {
      #pragma unroll
      for (int r = 0; r < 4; ++r) {
        int grow = m0 + wr * 64 + mf * 16 + (lane >> 4) * 4 + r;
        #pragma unroll
        for (int nf = 0; nf < 4; ++nf) {
          int gcol = n0 + wc * 64 + nf * 16 + (lane & 15);
          Cout[(size_t)grow * ldc + gcol] = acc[mf][nf][r];
        }
      }
    }
  } else {
    float b2v[4];
    #pragma unroll
    for (int nf = 0; nf < 4; ++nf)
      b2v[nf] = bias[n0 + wc * 64 + nf * 16 + (lane & 15)];
    #pragma unroll
    for (int mf = 0; mf < 4; ++mf) {
      #pragma unroll
      for (int r = 0; r < 4; ++r) {
        float s = 0.f;
        #pragma unroll
        for (int nf = 0; nf < 4; ++nf)
          s += __expf(acc[mf][nf][r] + b2v[nf]);
        s += __shfl_xor(s, 1); s += __shfl_xor(s, 2);
        s += __shfl_xor(s, 4); s += __shfl_xor(s, 8);
        if ((lane & 15) == 0)
          atomicAdd(&sumexp[m0 + wr * 64 + mf * 16 + (lane >> 4) * 4 + r], s);
      }
    }
  }
}

// act[p*8+b][c] = relu(Uw[iu*8+b][c] + Vw[ju*8+b][c] + b1[c]) as bf16; pad rows -> 0
__global__ __launch_bounds__(256) void k_act(const float* __restrict__ Uw, const float* __restrict__ Vw,
                                             const float* __restrict__ b1, bf16_t* __restrict__ act) {
  int p = blockIdx.x;                 // 0..1967
  int iu = 0, ju = 0;
  bool real = (p < NPTOT);
  if (p < NPAIR) {
    int i = 0, base = 0;
    while (base + (62 - i) <= p) { base += 62 - i; ++i; }
    iu = i; ju = i + 1 + (p - base);
  }                                   // p==1953 -> (0,0)
  for (int idx = threadIdx.x; idx < BB * HH; idx += 256) {
    int b = idx >> 9, c = idx & 511;
    float v = 0.f;
    if (real) {
      v = Uw[(size_t)(iu * BB + b) * HH + c] + Vw[(size_t)(ju * BB + b) * HH + c] + b1[c];
      v = fmaxf(v, 0.f);
    }
    act[(size_t)(p * BB + b) * HH + c] = (bf16_t)v;
  }
}

// t-network: one wave per (i,j,b) row
__global__ __launch_bounds__(256) void k_tnet(const float* __restrict__ Ut, const float* __restrict__ Vt,
                                              const float* __restrict__ b1, const float* __restrict__ W2,
                                              const float* __restrict__ b2,
                                              float* __restrict__ sh_lp, float* __restrict__ re_lp) {
  int gid = blockIdx.x * 4 + (threadIdx.x >> 6);  // 0..32767 = (i*64+j)*8+b
  int lane = threadIdx.x & 63;
  int b = gid & 7, j = (gid >> 3) & 63, i = gid >> 9;
  const float4* u = (const float4*)(Ut + (size_t)(i * BB + b) * HH);
  const float4* v = (const float4*)(Vt + (size_t)(j * BB + b) * HH);
  const float4* bb = (const float4*)b1;
  const float4* ww = (const float4*)W2;
  float s = 0.f;
  #pragma unroll
  for (int q = 0; q < 2; ++q) {
    int c = lane * 2 + q;
    float4 uu = u[c], vv = v[c], b4 = bb[c], w4 = ww[c];
    s += fmaxf(uu.x + vv.x + b4.x, 0.f) * w4.x;
    s += fmaxf(uu.y + vv.y + b4.y, 0.f) * w4.y;
    s += fmaxf(uu.z + vv.z + b4.z, 0.f) * w4.z;
    s += fmaxf(uu.w + vv.w + b4.w, 0.f) * w4.w;
  }
  #pragma unroll
  for (int off = 1; off < 64; off <<= 1) s += __shfl_xor(s, off);
  if (lane == 0) {
    float t = s + b2[0];
    re_lp[gid] = logsig(t);
    sh_lp[gid] = logsig(-t);
  }
}

// tok_logit[r] = dot(act[r], w_W2T[tok]) + b2[tok]
__global__ __launch_bounds__(256) void k_toklogit(const bf16_t* __restrict__ act, const bf16_t* __restrict__ W2T,
                                                  const float* __restrict__ b2, const int* __restrict__ sent,
                                                  float* __restrict__ tok_logit) {
  int r = blockIdx.x * 4 + (threadIdx.x >> 6);  // 0..15631
  int lane = threadIdx.x & 63;
  int p = r >> 3, b = r & 7;
  int tok;
  if (p >= NPAIR) {
    tok = sent[1 * BB + b];
  } else {
    int i = 0, base = 0;
    while (base + (62 - i) <= p) { base += 62 - i; ++i; }
    int ju = i + 1 + (p - base);
    tok = sent[(ju + 1) * BB + b];
  }
  const bf16x8* av = (const bf16x8*)(act + (size_t)r * HH);
  const bf16x8* wv = (const bf16x8*)(W2T + (size_t)tok * HH);
  bf16x8 a = av[lane], w = wv[lane];
  float s = 0.f;
  #pragma unroll
  for (int e = 0; e < 8; ++e) s += (float)a[e] * (float)w[e];
  #pragma unroll
  for (int off = 1; off < 64; off <<= 1) s += __shfl_xor(s, off);
  if (lane == 0) tok_logit[r] = s + b2[tok];
}

__global__ void k_wp(const float* __restrict__ sh_lp, const float* __restrict__ tok_logit,
                     const float* __restrict__ sumexp, float* __restrict__ wp) {
  int gid = blockIdx.x * blockDim.x + threadIdx.x;  // (i*64+j)*8+b
  int b = gid & 7, j = (gid >> 3) & 63, i = gid >> 9;
  float vv = NEG;
  if (i < j && j <= 62) {
    int p = i * 62 - i * (i - 1) / 2 + (j - i - 1);
    int r = p * 8 + b;
    vv = sh_lp[gid] + (tok_logit[r] - logf(sumexp[r]));
  }
  wp[gid] = vv;
}

// inside DP: one block per batch, table/wp/re_lp in LDS
__global__ __launch_bounds__(1024) void k_dp(const float* __restrict__ wp, const float* __restrict__ re_lp,
                                             const float* __restrict__ tok_logit, const float* __restrict__ sumexp,
                                             float* __restrict__ finals) {
  int b = blockIdx.x;
  __shared__ float tab[4096];
  __shared__ float wpl[4096];
  __shared__ float rel[4096];
  int tid = threadIdx.x;
  for (int idx = tid; idx < 4096; idx += 1024) {
    tab[idx] = NEG;
    wpl[idx] = wp[idx * 8 + b];
    rel[idx] = re_lp[idx * 8 + b];
  }
  __syncthreads();
  if (tid == 0) tab[1] = tok_logit[NPAIR * 8 + b] - logf(sumexp[NPAIR * 8 + b]);
  if (tid >= 1 && tid <= 62) tab[tid * 64 + tid + 1] = 0.f;
  __syncthreads();
  int lane = tid & 63, wave = tid >> 6;   // 16 waves
  for (int g = 2; g <= 63; ++g) {
    for (int i = wave; i + g <= 63; i += 16) {
      int j = i + g;
      int m = lane + 1;
      float sc = NEG;
      if (m < g) sc = tab[i * 64 + i + m] + tab[(i + m) * 64 + j] + wpl[i * 64 + i + m] + rel[(i + m) * 64 + j];
      float mx = sc;
      #pragma unroll
      for (int off = 1; off < 64; off <<= 1) mx = fmaxf(mx, __shfl_xor(mx, off));
      float e = (m < g) ? expf(sc - mx) : 0.f;
      #pragma unroll
      for (int off = 1; off < 64; off <<= 1) e += __shfl_xor(e, off);
      if (lane == 0) tab[i * 64 + j] = logf(e) + mx;
    }
    __syncthreads();
  }
  if (tid == 0) finals[b] = tab[63] + rel[63];
}

__global__ void k_final(const float* __restrict__ finals, float* __restrict__ out) {
  if (threadIdx.x == 0) {
    float s = 0.f;
    for (int b = 0; b < 8; ++b) s += finals[b];
    out[0] = -s;
  }
}

extern "C" void kernel_launch(void* const* d_in, const int* in_sizes, int n_in,
                              void* d_out, int out_size, void* d_ws, size_t ws_size,
                              hipStream_t stream) {
  const float* h    = (const float*)d_in[0];
  const int*   sent = (const int*)d_in[1];
  const float* tW1  = (const float*)d_in[2];
  const float* tb1  = (const float*)d_in[3];
  const float* tW2  = (const float*)d_in[4];
  const float* tb2  = (const float*)d_in[5];
  const float* wW1  = (const float*)d_in[6];
  const float* wb1  = (const float*)d_in[7];
  const float* wW2  = (const float*)d_in[8];
  const float* wb2  = (const float*)d_in[9];
  float* out = (float*)d_out;

  char* ws = (char*)d_ws;
  size_t off = 0;
  auto alloc = [&](size_t bytes) { char* p = ws + off; off += (bytes + 255) & ~(size_t)255; return p; };
  bf16_t* hbf    = (bf16_t*)alloc((size_t)512 * 512 * 2);
  bf16_t* tW1T   = (bf16_t*)alloc((size_t)512 * 1024 * 2);
  bf16_t* wW1T   = (bf16_t*)alloc((size_t)512 * 1024 * 2);
  bf16_t* wW2T   = (bf16_t*)alloc((size_t)VV * HH * 2);
  float*  Ut     = (float*)alloc((size_t)512 * 512 * 4);
  float*  Vt     = (float*)alloc((size_t)512 * 512 * 4);
  float*  Uw     = (float*)alloc((size_t)512 * 512 * 4);
  float*  Vw     = (float*)alloc((size_t)512 * 512 * 4);
  bf16_t* act    = (bf16_t*)alloc((size_t)MPAD * HH * 2);
  float*  sumexp = (float*)alloc((size_t)MPAD * 4);
  float*  tokl   = (float*)alloc((size_t)MPAD * 4);
  float*  shlp   = (float*)alloc((size_t)32768 * 4);
  float*  relp   = (float*)alloc((size_t)32768 * 4);
  float*  wpb    = (float*)alloc((size_t)32768 * 4);
  float*  finals = (float*)alloc(256);

  k_zero<<<(MPAD + 255) / 256, 256, 0, stream>>>(sumexp, MPAD);
  k_cvt<<<(262144 + 255) / 256, 256, 0, stream>>>(h, hbf, 262144);
  dim3 tg1(512 / 32, 1024 / 32);
  k_tcvt<<<tg1, 256, 0, stream>>>(tW1, tW1T, 1024, 512);
  k_tcvt<<<tg1, 256, 0, stream>>>(wW1, wW1T, 1024, 512);
  dim3 tg2(8192 / 32, 512 / 32);
  k_tcvt<<<tg2, 256, 0, stream>>>(wW2, wW2T, 512, 8192);

  dim3 gs(4, 4);
  k_gemm<0><<<gs, 256, 0, stream>>>(hbf, 512, tW1T,       1024, Ut, 512, nullptr, nullptr, 512);
  k_gemm<0><<<gs, 256, 0, stream>>>(hbf, 512, tW1T + 512, 1024, Vt, 512, nullptr, nullptr, 512);
  k_gemm<0><<<gs, 256, 0, stream>>>(hbf, 512, wW1T,       1024, Uw, 512, nullptr, nullptr, 512);
  k_gemm<0><<<gs, 256, 0, stream>>>(hbf, 512, wW1T + 512, 1024, Vw, 512, nullptr, nullptr, 512);

  k_act<<<MPAD / 8, 256, 0, stream>>>(Uw, Vw, wb1, act);
  k_tnet<<<32768 / 4, 256, 0, stream>>>(Ut, Vt, tb1, tW2, tb2, shlp, relp);

  dim3 gb(MPAD / 128, VV / 128);
  k_gemm<1><<<gb, 256, 0, stream>>>(act, 512, wW2T, 512, nullptr, 0, wb2, sumexp, 512);

  k_toklogit<<<MROWS / 4, 256, 0, stream>>>(act, wW2T, wb2, sent, tokl);
  k_wp<<<32768 / 256, 256, 0, stream>>>(shlp, tokl, sumexp, wpb);
  k_dp<<<8, 1024, 0, stream>>>(wpb, relp, tokl, sumexp, finals);
  k_final<<<1, 64, 0, stream>>>(finals, out);
}

// Round 2
// 403.249 us; speedup vs baseline: 1.1210x; 1.1210x over previous
//
#include <hip/hip_runtime.h>
#include <hip/hip_bf16.h>
#include <math.h>

#define NEG (-1.0e9f)

typedef __bf16 bf16_t;
typedef __bf16 bf16x8 __attribute__((ext_vector_type(8)));
typedef float f32x4 __attribute__((ext_vector_type(4)));

#define SS 64
#define BB 8
#define HH 512
#define VV 8192
#define NPAIR 1953          /* upper-tri pairs (i<j) over [0,63) */
#define NPTOT 1954          /* + (0,0) row for init_lp */
#define MROWS (NPTOT*BB)    /* 15632 */
#define MPAD  15744         /* 123*128 */

__device__ __forceinline__ float logsig(float x) {
  return fminf(x, 0.f) - __logf(1.f + __expf(-fabsf(x)));
}

__global__ void k_cvt(const float* __restrict__ in, bf16_t* __restrict__ out, int n) {
  int i = blockIdx.x * blockDim.x + threadIdx.x;
  if (i < n) out[i] = (bf16_t)in[i];
}

// transpose fp32 (R x C) -> bf16 (C x R)
__global__ __launch_bounds__(256) void k_tcvt(const float* __restrict__ in, bf16_t* __restrict__ out,
                                              int R, int C) {
  __shared__ float tile[32][33];
  int c0 = blockIdx.x * 32, r0 = blockIdx.y * 32;
  int tx = threadIdx.x & 31, ty = threadIdx.x >> 5;
  for (int i = ty; i < 32; i += 8)
    tile[i][tx] = in[(size_t)(r0 + i) * C + c0 + tx];
  __syncthreads();
  for (int i = ty; i < 32; i += 8)
    out[(size_t)(c0 + i) * R + r0 + tx] = (bf16_t)tile[tx][i];
}

// C = A(MxK) @ BT(NxK)^T.  MODE 0: store fp32 C. MODE 1: sumexp[row] += sum_col exp(C+bias)
// 1-D grid; XCD-chunk + grouped-M swizzle for per-XCD L2 locality.
template<int MODE>
__global__ __launch_bounds__(256) void k_gemm(
    const bf16_t* __restrict__ A, int lda,
    const bf16_t* __restrict__ BT, int ldb,
    float* __restrict__ Cout, int ldc,
    const float* __restrict__ bias,
    float* __restrict__ sumexp,
    int K, int num_m, int num_n)
{
  __shared__ __align__(16) bf16_t As[128 * 32];
  __shared__ __align__(16) bf16_t Bs[128 * 32];
  const int tid = threadIdx.x;
  const int lane = tid & 63;
  const int wave = tid >> 6;
  const int wr = wave >> 1, wc = wave & 1;

  // ---- block swizzle: bijective XCD chunk (m204), then grouped-M (GM=8) ----
  const int nwg = num_m * num_n;
  const int pid = blockIdx.x;
  const int q = nwg >> 3, r = nwg & 7;
  const int xcd = pid & 7, sub = pid >> 3;
  const int wg = (xcd < r ? xcd * (q + 1) : r * (q + 1) + (xcd - r) * q) + sub;
  const int GM = 8;
  const int npg = GM * num_n;
  const int gidg = wg / npg;
  const int first = gidg * GM;
  int gsz = num_m - first; if (gsz > GM) gsz = GM;
  const int local = wg - gidg * npg;
  const int mt = first + local % gsz;
  const int nt = local / gsz;
  const int m0 = mt * 128, n0 = nt * 128;

  const int rowS = tid >> 2;          // 0..63
  const int kS = (tid & 3) * 8;
  const bf16_t* gA0 = A + (size_t)(m0 + rowS) * lda + kS;
  const bf16_t* gA1 = A + (size_t)(m0 + rowS + 64) * lda + kS;
  const bf16_t* gB0 = BT + (size_t)(n0 + rowS) * ldb + kS;
  const bf16_t* gB1 = BT + (size_t)(n0 + rowS + 64) * ldb + kS;

  f32x4 acc[4][4] = {};

  const int aoff = (wr * 64 + (lane & 15)) * 32 + (lane >> 4) * 8;
  const int boff = (wc * 64 + (lane & 15)) * 32 + (lane >> 4) * 8;

  for (int k0 = 0; k0 < K; k0 += 32) {
    __builtin_amdgcn_global_load_lds((const __attribute__((address_space(1))) void*)(gA0 + k0),
        (__attribute__((address_space(3))) void*)(As + wave * 512), 16, 0, 0);
    __builtin_amdgcn_global_load_lds((const __attribute__((address_space(1))) void*)(gA1 + k0),
        (__attribute__((address_space(3))) void*)(As + 2048 + wave * 512), 16, 0, 0);
    __builtin_amdgcn_global_load_lds((const __attribute__((address_space(1))) void*)(gB0 + k0),
        (__attribute__((address_space(3))) void*)(Bs + wave * 512), 16, 0, 0);
    __builtin_amdgcn_global_load_lds((const __attribute__((address_space(1))) void*)(gB1 + k0),
        (__attribute__((address_space(3))) void*)(Bs + 2048 + wave * 512), 16, 0, 0);
    __syncthreads();

    bf16x8 af[4], bfr[4];
    #pragma unroll
    for (int mf = 0; mf < 4; ++mf)
      af[mf] = *(const bf16x8*)&As[aoff + mf * 16 * 32];
    #pragma unroll
    for (int nf = 0; nf < 4; ++nf)
      bfr[nf] = *(const bf16x8*)&Bs[boff + nf * 16 * 32];
    #pragma unroll
    for (int mf = 0; mf < 4; ++mf)
      #pragma unroll
      for (int nf = 0; nf < 4; ++nf)
        acc[mf][nf] = __builtin_amdgcn_mfma_f32_16x16x32_bf16(af[mf], bfr[nf], acc[mf][nf], 0, 0, 0);
    __syncthreads();
  }

  if (MODE == 0) {
    #pragma unroll
    for (int mf = 0; mf < 4; ++mf) {
      #pragma unroll
      for (int r2 = 0; r2 < 4; ++r2) {
        int grow = m0 + wr * 64 + mf * 16 + (lane >> 4) * 4 + r2;
        #pragma unroll
        for (int nf = 0; nf < 4; ++nf) {
          int gcol = n0 + wc * 64 + nf * 16 + (lane & 15);
          Cout[(size_t)grow * ldc + gcol] = acc[mf][nf][r2];
        }
      }
    }
  } else {
    float b2v[4];
    #pragma unroll
    for (int nf = 0; nf < 4; ++nf)
      b2v[nf] = bias[n0 + wc * 64 + nf * 16 + (lane & 15)];
    #pragma unroll
    for (int mf = 0; mf < 4; ++mf) {
      #pragma unroll
      for (int r2 = 0; r2 < 4; ++r2) {
        float s = 0.f;
        #pragma unroll
        for (int nf = 0; nf < 4; ++nf)
          s += __expf(acc[mf][nf][r2] + b2v[nf]);
        s += __shfl_xor(s, 1); s += __shfl_xor(s, 2);
        s += __shfl_xor(s, 4); s += __shfl_xor(s, 8);
        if ((lane & 15) == 0)
          atomicAdd(&sumexp[m0 + wr * 64 + mf * 16 + (lane >> 4) * 4 + r2], s);
      }
    }
  }
}

// act[p*8+b][c] = relu(Uw[iu*8+b][c] + Vw[ju*8+b][c] + b1[c]) as bf16; pad rows -> 0
// also zeroes sumexp rows it owns (folded k_zero)
__global__ __launch_bounds__(256) void k_act(const float* __restrict__ Uw, const float* __restrict__ Vw,
                                             const float* __restrict__ b1, bf16_t* __restrict__ act,
                                             float* __restrict__ sumexp) {
  int p = blockIdx.x;                 // 0..1967
  if (threadIdx.x < 8) sumexp[p * 8 + threadIdx.x] = 0.f;
  int iu = 0, ju = 0;
  bool real = (p < NPTOT);
  if (p < NPAIR) {
    int i = 0, base = 0;
    while (base + (62 - i) <= p) { base += 62 - i; ++i; }
    iu = i; ju = i + 1 + (p - base);
  }                                   // p==1953 -> (0,0)
  for (int idx = threadIdx.x; idx < BB * HH; idx += 256) {
    int b = idx >> 9, c = idx & 511;
    float v = 0.f;
    if (real) {
      v = Uw[(size_t)(iu * BB + b) * HH + c] + Vw[(size_t)(ju * BB + b) * HH + c] + b1[c];
      v = fmaxf(v, 0.f);
    }
    act[(size_t)(p * BB + b) * HH + c] = (bf16_t)v;
  }
}

// t-network: one wave per (i,j,b) row
__global__ __launch_bounds__(256) void k_tnet(const float* __restrict__ Ut, const float* __restrict__ Vt,
                                              const float* __restrict__ b1, const float* __restrict__ W2,
                                              const float* __restrict__ b2,
                                              float* __restrict__ sh_lp, float* __restrict__ re_lp) {
  int gid = blockIdx.x * 4 + (threadIdx.x >> 6);  // 0..32767 = (i*64+j)*8+b
  int lane = threadIdx.x & 63;
  int b = gid & 7, j = (gid >> 3) & 63, i = gid >> 9;
  const float4* u = (const float4*)(Ut + (size_t)(i * BB + b) * HH);
  const float4* v = (const float4*)(Vt + (size_t)(j * BB + b) * HH);
  const float4* bb = (const float4*)b1;
  const float4* ww = (const float4*)W2;
  float s = 0.f;
  #pragma unroll
  for (int qq = 0; qq < 2; ++qq) {
    int c = lane * 2 + qq;
    float4 uu = u[c], vv = v[c], b4 = bb[c], w4 = ww[c];
    s += fmaxf(uu.x + vv.x + b4.x, 0.f) * w4.x;
    s += fmaxf(uu.y + vv.y + b4.y, 0.f) * w4.y;
    s += fmaxf(uu.z + vv.z + b4.z, 0.f) * w4.z;
    s += fmaxf(uu.w + vv.w + b4.w, 0.f) * w4.w;
  }
  #pragma unroll
  for (int off = 1; off < 64; off <<= 1) s += __shfl_xor(s, off);
  if (lane == 0) {
    float t = s + b2[0];
    re_lp[gid] = logsig(t);
    sh_lp[gid] = logsig(-t);
  }
}

// tok_logit[r] = dot(act[r], w_W2T[tok]) + b2[tok]
__global__ __launch_bounds__(256) void k_toklogit(const bf16_t* __restrict__ act, const bf16_t* __restrict__ W2T,
                                                  const float* __restrict__ b2, const int* __restrict__ sent,
                                                  float* __restrict__ tok_logit) {
  int r = blockIdx.x * 4 + (threadIdx.x >> 6);  // 0..15631
  int lane = threadIdx.x & 63;
  int p = r >> 3, b = r & 7;
  int tok;
  if (p >= NPAIR) {
    tok = sent[1 * BB + b];
  } else {
    int i = 0, base = 0;
    while (base + (62 - i) <= p) { base += 62 - i; ++i; }
    int ju = i + 1 + (p - base);
    tok = sent[(ju + 1) * BB + b];
  }
  const bf16x8* av = (const bf16x8*)(act + (size_t)r * HH);
  const bf16x8* wv = (const bf16x8*)(W2T + (size_t)tok * HH);
  bf16x8 a = av[lane], w = wv[lane];
  float s = 0.f;
  #pragma unroll
  for (int e = 0; e < 8; ++e) s += (float)a[e] * (float)w[e];
  #pragma unroll
  for (int off = 1; off < 64; off <<= 1) s += __shfl_xor(s, off);
  if (lane == 0) tok_logit[r] = s + b2[tok];
}

__global__ void k_wp(const float* __restrict__ sh_lp, const float* __restrict__ tok_logit,
                     const float* __restrict__ sumexp, float* __restrict__ wp) {
  int gid = blockIdx.x * blockDim.x + threadIdx.x;  // (i*64+j)*8+b
  int b = gid & 7, j = (gid >> 3) & 63, i = gid >> 9;
  float vv = NEG;
  if (i < j && j <= 62) {
    int p = i * 62 - i * (i - 1) / 2 + (j - i - 1);
    int r = p * 8 + b;
    vv = sh_lp[gid] + (tok_logit[r] - __logf(sumexp[r]));
  }
  wp[gid] = vv;
}

// inside DP: one block per batch, table/wp/re_lp in LDS
__global__ __launch_bounds__(1024) void k_dp(const float* __restrict__ wp, const float* __restrict__ re_lp,
                                             const float* __restrict__ tok_logit, const float* __restrict__ sumexp,
                                             float* __restrict__ finals) {
  int b = blockIdx.x;
  __shared__ float tab[4096];
  __shared__ float wpl[4096];
  __shared__ float rel[4096];
  int tid = threadIdx.x;
  for (int idx = tid; idx < 4096; idx += 1024) {
    tab[idx] = NEG;
    wpl[idx] = wp[idx * 8 + b];
    rel[idx] = re_lp[idx * 8 + b];
  }
  __syncthreads();
  if (tid == 0) tab[1] = tok_logit[NPAIR * 8 + b] - __logf(sumexp[NPAIR * 8 + b]);
  if (tid >= 1 && tid <= 62) tab[tid * 64 + tid + 1] = 0.f;
  __syncthreads();
  int lane = tid & 63, wave = tid >> 6;   // 16 waves
  for (int g = 2; g <= 63; ++g) {
    int cnt = 64 - g;                     // i in [0, 63-g]
    if (g <= 17) {
      // 16-lane segments: all i's in ONE pass (64 slots), m = 1..16 >= g-1
      int seg = lane >> 4, sl = lane & 15;
      int i = wave * 4 + seg;
      if (i < cnt) {
        int m = sl + 1;
        int j = i + g, k = i + m;
        float sc = NEG;
        if (m < g) sc = tab[i * 64 + k] + tab[k * 64 + j] + wpl[i * 64 + k] + rel[k * 64 + j];
        float mx = sc;
        #pragma unroll
        for (int off = 1; off < 16; off <<= 1) mx = fmaxf(mx, __shfl_xor(mx, off));
        float e = (m < g) ? __expf(sc - mx) : 0.f;
        #pragma unroll
        for (int off = 1; off < 16; off <<= 1) e += __shfl_xor(e, off);
        if (sl == 0) tab[i * 64 + j] = __logf(e) + mx;
      }
    } else {
      for (int i = wave; i < cnt; i += 16) {
        int m = lane + 1;
        int j = i + g, k = i + m;
        float sc = NEG;
        if (m < g) sc = tab[i * 64 + k] + tab[k * 64 + j] + wpl[i * 64 + k] + rel[k * 64 + j];
        float mx = sc;
        #pragma unroll
        for (int off = 1; off < 64; off <<= 1) mx = fmaxf(mx, __shfl_xor(mx, off));
        float e = (m < g) ? __expf(sc - mx) : 0.f;
        #pragma unroll
        for (int off = 1; off < 64; off <<= 1) e += __shfl_xor(e, off);
        if (lane == 0) tab[i * 64 + j] = __logf(e) + mx;
      }
    }
    __syncthreads();
  }
  if (tid == 0) finals[b] = tab[63] + rel[63];
}

__global__ void k_final(const float* __restrict__ finals, float* __restrict__ out) {
  if (threadIdx.x == 0) {
    float s = 0.f;
    for (int b = 0; b < 8; ++b) s += finals[b];
    out[0] = -s;
  }
}

extern "C" void kernel_launch(void* const* d_in, const int* in_sizes, int n_in,
                              void* d_out, int out_size, void* d_ws, size_t ws_size,
                              hipStream_t stream) {
  const float* h    = (const float*)d_in[0];
  const int*   sent = (const int*)d_in[1];
  const float* tW1  = (const float*)d_in[2];
  const float* tb1  = (const float*)d_in[3];
  const float* tW2  = (const float*)d_in[4];
  const float* tb2  = (const float*)d_in[5];
  const float* wW1  = (const float*)d_in[6];
  const float* wb1  = (const float*)d_in[7];
  const float* wW2  = (const float*)d_in[8];
  const float* wb2  = (const float*)d_in[9];
  float* out = (float*)d_out;

  char* ws = (char*)d_ws;
  size_t off = 0;
  auto alloc = [&](size_t bytes) { char* p = ws + off; off += (bytes + 255) & ~(size_t)255; return p; };
  bf16_t* hbf    = (bf16_t*)alloc((size_t)512 * 512 * 2);
  bf16_t* tW1T   = (bf16_t*)alloc((size_t)512 * 1024 * 2);
  bf16_t* wW1T   = (bf16_t*)alloc((size_t)512 * 1024 * 2);
  bf16_t* wW2T   = (bf16_t*)alloc((size_t)VV * HH * 2);
  float*  Ut     = (float*)alloc((size_t)512 * 512 * 4);
  float*  Vt     = (float*)alloc((size_t)512 * 512 * 4);
  float*  Uw     = (float*)alloc((size_t)512 * 512 * 4);
  float*  Vw     = (float*)alloc((size_t)512 * 512 * 4);
  bf16_t* act    = (bf16_t*)alloc((size_t)MPAD * HH * 2);
  float*  sumexp = (float*)alloc((size_t)MPAD * 4);
  float*  tokl   = (float*)alloc((size_t)MPAD * 4);
  float*  shlp   = (float*)alloc((size_t)32768 * 4);
  float*  relp   = (float*)alloc((size_t)32768 * 4);
  float*  wpb    = (float*)alloc((size_t)32768 * 4);
  float*  finals = (float*)alloc(256);

  k_cvt<<<(262144 + 255) / 256, 256, 0, stream>>>(h, hbf, 262144);
  dim3 tg1(512 / 32, 1024 / 32);
  k_tcvt<<<tg1, 256, 0, stream>>>(tW1, tW1T, 1024, 512);
  k_tcvt<<<tg1, 256, 0, stream>>>(wW1, wW1T, 1024, 512);
  dim3 tg2(8192 / 32, 512 / 32);
  k_tcvt<<<tg2, 256, 0, stream>>>(wW2, wW2T, 512, 8192);

  k_gemm<0><<<16, 256, 0, stream>>>(hbf, 512, tW1T,       1024, Ut, 512, nullptr, nullptr, 512, 4, 4);
  k_gemm<0><<<16, 256, 0, stream>>>(hbf, 512, tW1T + 512, 1024, Vt, 512, nullptr, nullptr, 512, 4, 4);
  k_gemm<0><<<16, 256, 0, stream>>>(hbf, 512, wW1T,       1024, Uw, 512, nullptr, nullptr, 512, 4, 4);
  k_gemm<0><<<16, 256, 0, stream>>>(hbf, 512, wW1T + 512, 1024, Vw, 512, nullptr, nullptr, 512, 4, 4);

  k_act<<<MPAD / 8, 256, 0, stream>>>(Uw, Vw, wb1, act, sumexp);
  k_tnet<<<32768 / 4, 256, 0, stream>>>(Ut, Vt, tb1, tW2, tb2, shlp, relp);

  k_gemm<1><<<(MPAD / 128) * (VV / 128), 256, 0, stream>>>(act, 512, wW2T, 512, nullptr, 0, wb2, sumexp, 512, MPAD / 128, VV / 128);

  k_toklogit<<<MROWS / 4, 256, 0, stream>>>(act, wW2T, wb2, sent, tokl);
  k_wp<<<32768 / 256, 256, 0, stream>>>(shlp, tokl, sumexp, wpb);
  k_dp<<<8, 1024, 0, stream>>>(wpb, relp, tokl, sumexp, finals);
  k_final<<<1, 64, 0, stream>>>(finals, out);
}

// Round 3
// 365.894 us; speedup vs baseline: 1.2355x; 1.1021x over previous
//
#include <hip/hip_runtime.h>
#include <hip/hip_bf16.h>
#include <math.h>

#define NEG (-1.0e9f)

typedef __bf16 bf16_t;
typedef __bf16 bf16x8 __attribute__((ext_vector_type(8)));
typedef float f32x4 __attribute__((ext_vector_type(4)));

#define SS 64
#define BB 8
#define HH 512
#define VV 8192
#define NPAIR 1953          /* upper-tri pairs (i<j) over [0,63) */
#define NPTOT 1954          /* + (0,0) row for init_lp */
#define MROWS (NPTOT*BB)    /* 15632 */
#define MPAD  15872         /* 62*256 */

__device__ __forceinline__ float logsig(float x) {
  return fminf(x, 0.f) - __logf(1.f + __expf(-fabsf(x)));
}

__global__ void k_cvt(const float* __restrict__ in, bf16_t* __restrict__ out, int n) {
  int i = blockIdx.x * blockDim.x + threadIdx.x;
  if (i < n) out[i] = (bf16_t)in[i];
}

// transpose fp32 (R x C) -> bf16 (C x R)
__global__ __launch_bounds__(256) void k_tcvt(const float* __restrict__ in, bf16_t* __restrict__ out,
                                              int R, int C) {
  __shared__ float tile[32][33];
  int c0 = blockIdx.x * 32, r0 = blockIdx.y * 32;
  int tx = threadIdx.x & 31, ty = threadIdx.x >> 5;
  for (int i = ty; i < 32; i += 8)
    tile[i][tx] = in[(size_t)(r0 + i) * C + c0 + tx];
  __syncthreads();
  for (int i = ty; i < 32; i += 8)
    out[(size_t)(c0 + i) * R + r0 + tx] = (bf16_t)tile[tx][i];
}

// ---------------- small 128x128-tile GEMM (MODE 0 only, for the 4 512^3 GEMMs) ------------
__global__ __launch_bounds__(256) void k_gemm128(
    const bf16_t* __restrict__ A, int lda,
    const bf16_t* __restrict__ BT, int ldb,
    float* __restrict__ Cout, int ldc,
    int K, int num_m, int num_n)
{
  __shared__ __align__(16) bf16_t As[128 * 32];
  __shared__ __align__(16) bf16_t Bs[128 * 32];
  const int tid = threadIdx.x;
  const int lane = tid & 63;
  const int wave = tid >> 6;
  const int wr = wave >> 1, wc = wave & 1;
  const int mt = blockIdx.x % num_m, nt = blockIdx.x / num_m;
  const int m0 = mt * 128, n0 = nt * 128;

  const int rowS = tid >> 2;
  const int kS = (tid & 3) * 8;
  const bf16_t* gA0 = A + (size_t)(m0 + rowS) * lda + kS;
  const bf16_t* gA1 = A + (size_t)(m0 + rowS + 64) * lda + kS;
  const bf16_t* gB0 = BT + (size_t)(n0 + rowS) * ldb + kS;
  const bf16_t* gB1 = BT + (size_t)(n0 + rowS + 64) * ldb + kS;

  f32x4 acc[4][4] = {};
  const int aoff = (wr * 64 + (lane & 15)) * 32 + (lane >> 4) * 8;
  const int boff = (wc * 64 + (lane & 15)) * 32 + (lane >> 4) * 8;

  for (int k0 = 0; k0 < K; k0 += 32) {
    __builtin_amdgcn_global_load_lds((const __attribute__((address_space(1))) void*)(gA0 + k0),
        (__attribute__((address_space(3))) void*)(As + wave * 512), 16, 0, 0);
    __builtin_amdgcn_global_load_lds((const __attribute__((address_space(1))) void*)(gA1 + k0),
        (__attribute__((address_space(3))) void*)(As + 2048 + wave * 512), 16, 0, 0);
    __builtin_amdgcn_global_load_lds((const __attribute__((address_space(1))) void*)(gB0 + k0),
        (__attribute__((address_space(3))) void*)(Bs + wave * 512), 16, 0, 0);
    __builtin_amdgcn_global_load_lds((const __attribute__((address_space(1))) void*)(gB1 + k0),
        (__attribute__((address_space(3))) void*)(Bs + 2048 + wave * 512), 16, 0, 0);
    __syncthreads();
    bf16x8 af[4], bfr[4];
    #pragma unroll
    for (int mf = 0; mf < 4; ++mf) af[mf] = *(const bf16x8*)&As[aoff + mf * 16 * 32];
    #pragma unroll
    for (int nf = 0; nf < 4; ++nf) bfr[nf] = *(const bf16x8*)&Bs[boff + nf * 16 * 32];
    #pragma unroll
    for (int mf = 0; mf < 4; ++mf)
      #pragma unroll
      for (int nf = 0; nf < 4; ++nf)
        acc[mf][nf] = __builtin_amdgcn_mfma_f32_16x16x32_bf16(af[mf], bfr[nf], acc[mf][nf], 0, 0, 0);
    __syncthreads();
  }
  #pragma unroll
  for (int mf = 0; mf < 4; ++mf)
    #pragma unroll
    for (int r2 = 0; r2 < 4; ++r2) {
      int grow = m0 + wr * 64 + mf * 16 + (lane >> 4) * 4 + r2;
      #pragma unroll
      for (int nf = 0; nf < 4; ++nf) {
        int gcol = n0 + wc * 64 + nf * 16 + (lane & 15);
        Cout[(size_t)grow * ldc + gcol] = acc[mf][nf][r2];
      }
    }
}

// ---------------- 256x256-tile 8-phase GEMM + fused exp-sum epilogue ----------------------
// A: MPAD x 512 bf16 (row-major), BT: 8192 x 512 bf16 (row-major, rows = output cols)
// sumexp[row] += sum_cols exp(A@BT^T + bias[col])
#define STAGEA(b, h, kt) do { \
  const bf16_t* _s = A + (size_t)(m0 + (h)*128 + (tid>>3)) * 512 + (kt)*64 + usrc; \
  __builtin_amdgcn_global_load_lds((const __attribute__((address_space(1))) void*)_s, \
    (__attribute__((address_space(3))) void*)(As + (b)*16384 + (h)*8192 + (tid>>6)*512), 16, 0, 0); \
  __builtin_amdgcn_global_load_lds((const __attribute__((address_space(1))) void*)(_s + (size_t)64*512), \
    (__attribute__((address_space(3))) void*)(As + (b)*16384 + (h)*8192 + 4096 + (tid>>6)*512), 16, 0, 0); \
} while(0)

#define STAGEB(b, h, kt) do { \
  const bf16_t* _s = BT + (size_t)(n0 + (h)*128 + (tid>>3)) * 512 + (kt)*64 + usrc; \
  __builtin_amdgcn_global_load_lds((const __attribute__((address_space(1))) void*)_s, \
    (__attribute__((address_space(3))) void*)(Bs + (b)*16384 + (h)*8192 + (tid>>6)*512), 16, 0, 0); \
  __builtin_amdgcn_global_load_lds((const __attribute__((address_space(1))) void*)(_s + (size_t)64*512), \
    (__attribute__((address_space(3))) void*)(Bs + (b)*16384 + (h)*8192 + 4096 + (tid>>6)*512), 16, 0, 0); \
} while(0)

#define LDA(b, mh) do { \
  _Pragma("unroll") \
  for (int _m = 0; _m < 4; ++_m) { \
    _Pragma("unroll") \
    for (int _k = 0; _k < 2; ++_k) \
      af[_m][_k] = *(const bf16x8*)(As + (b)*16384 + (mh)*8192 + aRowE + _m*1024 + uswz[_k]); \
  } \
} while(0)

#define LDB(b, nh) do { \
  _Pragma("unroll") \
  for (int _n = 0; _n < 2; ++_n) { \
    _Pragma("unroll") \
    for (int _k = 0; _k < 2; ++_k) \
      bfrag[nh][_n][_k] = *(const bf16x8*)(Bs + (b)*16384 + (nh)*8192 + bRowE + _n*1024 + uswz[_k]); \
  } \
} while(0)

#define MMA(mh, nh) do { \
  __builtin_amdgcn_s_setprio(1); \
  _Pragma("unroll") \
  for (int _m = 0; _m < 4; ++_m) \
    _Pragma("unroll") \
    for (int _n = 0; _n < 2; ++_n) \
      _Pragma("unroll") \
      for (int _k = 0; _k < 2; ++_k) \
        acc[(mh)*4+_m][(nh)*2+_n] = __builtin_amdgcn_mfma_f32_16x16x32_bf16( \
            af[_m][_k], bfrag[nh][_n][_k], acc[(mh)*4+_m][(nh)*2+_n], 0, 0, 0); \
  __builtin_amdgcn_s_setprio(0); \
} while(0)

#define BARLG() do { __builtin_amdgcn_s_barrier(); \
  asm volatile("s_waitcnt lgkmcnt(0)" ::: "memory"); \
  __builtin_amdgcn_sched_barrier(0); } while(0)
#define ENDPH() __builtin_amdgcn_s_barrier()
#define CKPT() asm volatile("s_waitcnt vmcnt(4)" ::: "memory")

__global__ __launch_bounds__(512, 2) void k_gemm256(
    const bf16_t* __restrict__ A,
    const bf16_t* __restrict__ BT,
    const float* __restrict__ bias,
    float* __restrict__ sumexp,
    int num_m, int num_n)
{
  __shared__ __align__(16) bf16_t As[2 * 16384];   // [buf][256 rows][64 k]
  __shared__ __align__(16) bf16_t Bs[2 * 16384];
  const int tid = threadIdx.x;
  const int l = tid & 63;
  const int wave = tid >> 6;
  const int wr = wave >> 2, wc = wave & 3;   // 2M x 4N waves

  // bijective XCD chunk + grouped-M swizzle
  const int nwg = num_m * num_n;
  const int pid = blockIdx.x;
  const int q = nwg >> 3, rr = nwg & 7;
  const int xcd = pid & 7, sub = pid >> 3;
  const int wg = (xcd < rr ? xcd * (q + 1) : rr * (q + 1) + (xcd - rr) * q) + sub;
  const int GM = 8;
  const int npg = GM * num_n;
  const int gidg = wg / npg;
  const int first = gidg * GM;
  int gsz = num_m - first; if (gsz > GM) gsz = GM;
  const int local = wg - gidg * npg;
  const int mt = first + local % gsz;
  const int nt = local / gsz;
  const int m0 = mt * 256, n0 = nt * 256;

  // staging: LDS[r][u] (linear) holds G[r][u ^ (r&7)], u = 16B unit (8 bf16)
  const int usrc = (((tid & 7) ^ ((tid >> 3) & 7)) << 3);
  // fragment read bases (element offsets); row%8 == l&7 for all fragments
  const int aRowE = (wr * 64 + (l & 15)) * 64;
  const int bRowE = (wc * 32 + (l & 15)) * 64;
  int uswz[2];
  uswz[0] = (((l >> 4) + 0) ^ (l & 7)) << 3;
  uswz[1] = (((l >> 4) + 4) ^ (l & 7)) << 3;

  f32x4 acc[8][4] = {};
  bf16x8 af[4][2];
  bf16x8 bfrag[2][2][2];

  // prologue: K-tile 0 -> buf0 (all 4 halves); K-tile 1 -> buf1.A0,B0
  STAGEA(0, 0, 0); STAGEA(0, 1, 0); STAGEB(0, 0, 0); STAGEB(0, 1, 0);
  STAGEA(1, 0, 1); STAGEB(1, 0, 1);
  CKPT();                      // oldest 8 issues (= K-tile 0) landed
  __builtin_amdgcn_s_barrier();

  // main loop: iter t computes K-tiles 2t (buf0, ph1-4) and 2t+1 (buf1, ph5-8)
  for (int t = 0; t < 4; ++t) {
    int tA = 2 * t + 1;
    int tB = 2 * t + 2; if (tB > 7) tB = 7;   // clamped prefetch (dead loads, race-safe)
    int tC = 2 * t + 3; if (tC > 7) tC = 7;
    // ph1 (m0,n0)  reads buf0.A0,B0 ; stages buf1.A1 (retired prev ph8)
    LDA(0, 0); LDB(0, 0);
    STAGEA(1, 1, tA);
    BARLG(); MMA(0, 0); ENDPH();
    // ph2 (m0,n1)  reads buf0.B1 ; stages buf1.B1 (retired prev ph8)
    LDB(0, 1);
    STAGEB(1, 1, tA);
    BARLG(); MMA(0, 1); ENDPH();
    // ph3 (m1,n0)  reads buf0.A1 ; stages buf0.A0 (retired ph2)
    LDA(0, 1);
    STAGEA(0, 0, tB);
    BARLG(); MMA(1, 0); ENDPH();
    // ph4 (m1,n1)  stages buf0.B0 (retired ph3) ; checkpoint: buf1 complete
    STAGEB(0, 0, tB);
    BARLG(); MMA(1, 1); CKPT(); ENDPH();
    // ph5 (m0,n0) on buf1 ; stages buf0.A1 (retired ph4)
    LDA(1, 0); LDB(1, 0);
    STAGEA(0, 1, tB);
    BARLG(); MMA(0, 0); ENDPH();
    // ph6 (m0,n1) ; stages buf0.B1 (retired ph4)
    LDB(1, 1);
    STAGEB(0, 1, tB);
    BARLG(); MMA(0, 1); ENDPH();
    // ph7 (m1,n0) ; stages buf1.A0 (retired ph6)
    LDA(1, 1);
    STAGEA(1, 0, tC);
    BARLG(); MMA(1, 0); ENDPH();
    // ph8 (m1,n1) ; stages buf1.B0 (retired ph7) ; checkpoint: buf0 complete
    STAGEB(1, 0, tC);
    BARLG(); MMA(1, 1); CKPT(); ENDPH();
  }

  // epilogue: sumexp[row] += sum over this block's 256 cols of exp(logit + bias)
  float b2v[4];
  #pragma unroll
  for (int nf = 0; nf < 4; ++nf)
    b2v[nf] = bias[n0 + (nf >> 1) * 128 + wc * 32 + (nf & 1) * 16 + (l & 15)];
  #pragma unroll
  for (int mf = 0; mf < 8; ++mf) {
    #pragma unroll
    for (int r2 = 0; r2 < 4; ++r2) {
      float s = 0.f;
      #pragma unroll
      for (int nf = 0; nf < 4; ++nf)
        s += __expf(acc[mf][nf][r2] + b2v[nf]);
      s += __shfl_xor(s, 1); s += __shfl_xor(s, 2);
      s += __shfl_xor(s, 4); s += __shfl_xor(s, 8);
      if ((l & 15) == 0)
        atomicAdd(&sumexp[m0 + (mf >> 2) * 128 + wr * 64 + (mf & 3) * 16 + (l >> 4) * 4 + r2], s);
    }
  }
}

// act[p*8+b][c] = relu(Uw[iu*8+b][c] + Vw[ju*8+b][c] + b1[c]) as bf16; pad rows -> 0
// also zeroes sumexp rows it owns (folded k_zero)
__global__ __launch_bounds__(256) void k_act(const float* __restrict__ Uw, const float* __restrict__ Vw,
                                             const float* __restrict__ b1, bf16_t* __restrict__ act,
                                             float* __restrict__ sumexp) {
  int p = blockIdx.x;                 // 0..1983
  if (threadIdx.x < 8) sumexp[p * 8 + threadIdx.x] = 0.f;
  int iu = 0, ju = 0;
  bool real = (p < NPTOT);
  if (p < NPAIR) {
    int i = 0, base = 0;
    while (base + (62 - i) <= p) { base += 62 - i; ++i; }
    iu = i; ju = i + 1 + (p - base);
  }                                   // p==1953 -> (0,0)
  for (int idx = threadIdx.x; idx < BB * HH; idx += 256) {
    int b = idx >> 9, c = idx & 511;
    float v = 0.f;
    if (real) {
      v = Uw[(size_t)(iu * BB + b) * HH + c] + Vw[(size_t)(ju * BB + b) * HH + c] + b1[c];
      v = fmaxf(v, 0.f);
    }
    act[(size_t)(p * BB + b) * HH + c] = (bf16_t)v;
  }
}

// t-network: one wave per (i,j,b) row
__global__ __launch_bounds__(256) void k_tnet(const float* __restrict__ Ut, const float* __restrict__ Vt,
                                              const float* __restrict__ b1, const float* __restrict__ W2,
                                              const float* __restrict__ b2,
                                              float* __restrict__ sh_lp, float* __restrict__ re_lp) {
  int gid = blockIdx.x * 4 + (threadIdx.x >> 6);  // 0..32767 = (i*64+j)*8+b
  int lane = threadIdx.x & 63;
  int b = gid & 7, j = (gid >> 3) & 63, i = gid >> 9;
  const float4* u = (const float4*)(Ut + (size_t)(i * BB + b) * HH);
  const float4* v = (const float4*)(Vt + (size_t)(j * BB + b) * HH);
  const float4* bb = (const float4*)b1;
  const float4* ww = (const float4*)W2;
  float s = 0.f;
  #pragma unroll
  for (int qq = 0; qq < 2; ++qq) {
    int c = lane * 2 + qq;
    float4 uu = u[c], vv = v[c], b4 = bb[c], w4 = ww[c];
    s += fmaxf(uu.x + vv.x + b4.x, 0.f) * w4.x;
    s += fmaxf(uu.y + vv.y + b4.y, 0.f) * w4.y;
    s += fmaxf(uu.z + vv.z + b4.z, 0.f) * w4.z;
    s += fmaxf(uu.w + vv.w + b4.w, 0.f) * w4.w;
  }
  #pragma unroll
  for (int off = 1; off < 64; off <<= 1) s += __shfl_xor(s, off);
  if (lane == 0) {
    float t = s + b2[0];
    re_lp[gid] = logsig(t);
    sh_lp[gid] = logsig(-t);
  }
}

// tok_logit[r] = dot(act[r], w_W2T[tok]) + b2[tok]
__global__ __launch_bounds__(256) void k_toklogit(const bf16_t* __restrict__ act, const bf16_t* __restrict__ W2T,
                                                  const float* __restrict__ b2, const int* __restrict__ sent,
                                                  float* __restrict__ tok_logit) {
  int r = blockIdx.x * 4 + (threadIdx.x >> 6);  // 0..15631
  int lane = threadIdx.x & 63;
  int p = r >> 3, b = r & 7;
  int tok;
  if (p >= NPAIR) {
    tok = sent[1 * BB + b];
  } else {
    int i = 0, base = 0;
    while (base + (62 - i) <= p) { base += 62 - i; ++i; }
    int ju = i + 1 + (p - base);
    tok = sent[(ju + 1) * BB + b];
  }
  const bf16x8* av = (const bf16x8*)(act + (size_t)r * HH);
  const bf16x8* wv = (const bf16x8*)(W2T + (size_t)tok * HH);
  bf16x8 a = av[lane], w = wv[lane];
  float s = 0.f;
  #pragma unroll
  for (int e = 0; e < 8; ++e) s += (float)a[e] * (float)w[e];
  #pragma unroll
  for (int off = 1; off < 64; off <<= 1) s += __shfl_xor(s, off);
  if (lane == 0) tok_logit[r] = s + b2[tok];
}

__global__ void k_wp(const float* __restrict__ sh_lp, const float* __restrict__ tok_logit,
                     const float* __restrict__ sumexp, float* __restrict__ wp) {
  int gid = blockIdx.x * blockDim.x + threadIdx.x;  // (i*64+j)*8+b
  int b = gid & 7, j = (gid >> 3) & 63, i = gid >> 9;
  float vv = NEG;
  if (i < j && j <= 62) {
    int p = i * 62 - i * (i - 1) / 2 + (j - i - 1);
    int r = p * 8 + b;
    vv = sh_lp[gid] + (tok_logit[r] - __logf(sumexp[r]));
  }
  wp[gid] = vv;
}

// inside DP: one block per batch, table/wp/re_lp in LDS
__global__ __launch_bounds__(1024) void k_dp(const float* __restrict__ wp, const float* __restrict__ re_lp,
                                             const float* __restrict__ tok_logit, const float* __restrict__ sumexp,
                                             float* __restrict__ finals) {
  int b = blockIdx.x;
  __shared__ float tab[4096];
  __shared__ float wpl[4096];
  __shared__ float rel[4096];
  int tid = threadIdx.x;
  for (int idx = tid; idx < 4096; idx += 1024) {
    tab[idx] = NEG;
    wpl[idx] = wp[idx * 8 + b];
    rel[idx] = re_lp[idx * 8 + b];
  }
  __syncthreads();
  if (tid == 0) tab[1] = tok_logit[NPAIR * 8 + b] - __logf(sumexp[NPAIR * 8 + b]);
  if (tid >= 1 && tid <= 62) tab[tid * 64 + tid + 1] = 0.f;
  __syncthreads();
  int lane = tid & 63, wave = tid >> 6;   // 16 waves
  for (int g = 2; g <= 63; ++g) {
    int cnt = 64 - g;                     // i in [0, 63-g]
    if (g <= 17) {
      int seg = lane >> 4, sl = lane & 15;
      int i = wave * 4 + seg;
      if (i < cnt) {
        int m = sl + 1;
        int j = i + g, k = i + m;
        float sc = NEG;
        if (m < g) sc = tab[i * 64 + k] + tab[k * 64 + j] + wpl[i * 64 + k] + rel[k * 64 + j];
        float mx = sc;
        #pragma unroll
        for (int off = 1; off < 16; off <<= 1) mx = fmaxf(mx, __shfl_xor(mx, off));
        float e = (m < g) ? __expf(sc - mx) : 0.f;
        #pragma unroll
        for (int off = 1; off < 16; off <<= 1) e += __shfl_xor(e, off);
        if (sl == 0) tab[i * 64 + j] = __logf(e) + mx;
      }
    } else {
      for (int i = wave; i < cnt; i += 16) {
        int m = lane + 1;
        int j = i + g, k = i + m;
        float sc = NEG;
        if (m < g) sc = tab[i * 64 + k] + tab[k * 64 + j] + wpl[i * 64 + k] + rel[k * 64 + j];
        float mx = sc;
        #pragma unroll
        for (int off = 1; off < 64; off <<= 1) mx = fmaxf(mx, __shfl_xor(mx, off));
        float e = (m < g) ? __expf(sc - mx) : 0.f;
        #pragma unroll
        for (int off = 1; off < 64; off <<= 1) e += __shfl_xor(e, off);
        if (lane == 0) tab[i * 64 + j] = __logf(e) + mx;
      }
    }
    __syncthreads();
  }
  if (tid == 0) finals[b] = tab[63] + rel[63];
}

__global__ void k_final(const float* __restrict__ finals, float* __restrict__ out) {
  if (threadIdx.x == 0) {
    float s = 0.f;
    for (int b = 0; b < 8; ++b) s += finals[b];
    out[0] = -s;
  }
}

extern "C" void kernel_launch(void* const* d_in, const int* in_sizes, int n_in,
                              void* d_out, int out_size, void* d_ws, size_t ws_size,
                              hipStream_t stream) {
  const float* h    = (const float*)d_in[0];
  const int*   sent = (const int*)d_in[1];
  const float* tW1  = (const float*)d_in[2];
  const float* tb1  = (const float*)d_in[3];
  const float* tW2  = (const float*)d_in[4];
  const float* tb2  = (const float*)d_in[5];
  const float* wW1  = (const float*)d_in[6];
  const float* wb1  = (const float*)d_in[7];
  const float* wW2  = (const float*)d_in[8];
  const float* wb2  = (const float*)d_in[9];
  float* out = (float*)d_out;

  char* ws = (char*)d_ws;
  size_t off = 0;
  auto alloc = [&](size_t bytes) { char* p = ws + off; off += (bytes + 255) & ~(size_t)255; return p; };
  bf16_t* hbf    = (bf16_t*)alloc((size_t)512 * 512 * 2);
  bf16_t* tW1T   = (bf16_t*)alloc((size_t)512 * 1024 * 2);
  bf16_t* wW1T   = (bf16_t*)alloc((size_t)512 * 1024 * 2);
  bf16_t* wW2T   = (bf16_t*)alloc((size_t)VV * HH * 2);
  float*  Ut     = (float*)alloc((size_t)512 * 512 * 4);
  float*  Vt     = (float*)alloc((size_t)512 * 512 * 4);
  float*  Uw     = (float*)alloc((size_t)512 * 512 * 4);
  float*  Vw     = (float*)alloc((size_t)512 * 512 * 4);
  bf16_t* act    = (bf16_t*)alloc((size_t)MPAD * HH * 2);
  float*  sumexp = (float*)alloc((size_t)MPAD * 4);
  float*  tokl   = (float*)alloc((size_t)MPAD * 4);
  float*  shlp   = (float*)alloc((size_t)32768 * 4);
  float*  relp   = (float*)alloc((size_t)32768 * 4);
  float*  wpb    = (float*)alloc((size_t)32768 * 4);
  float*  finals = (float*)alloc(256);

  k_cvt<<<(262144 + 255) / 256, 256, 0, stream>>>(h, hbf, 262144);
  dim3 tg1(512 / 32, 1024 / 32);
  k_tcvt<<<tg1, 256, 0, stream>>>(tW1, tW1T, 1024, 512);
  k_tcvt<<<tg1, 256, 0, stream>>>(wW1, wW1T, 1024, 512);
  dim3 tg2(8192 / 32, 512 / 32);
  k_tcvt<<<tg2, 256, 0, stream>>>(wW2, wW2T, 512, 8192);

  k_gemm128<<<16, 256, 0, stream>>>(hbf, 512, tW1T,       1024, Ut, 512, 512, 4, 4);
  k_gemm128<<<16, 256, 0, stream>>>(hbf, 512, tW1T + 512, 1024, Vt, 512, 512, 4, 4);
  k_gemm128<<<16, 256, 0, stream>>>(hbf, 512, wW1T,       1024, Uw, 512, 512, 4, 4);
  k_gemm128<<<16, 256, 0, stream>>>(hbf, 512, wW1T + 512, 1024, Vw, 512, 512, 4, 4);

  k_act<<<MPAD / 8, 256, 0, stream>>>(Uw, Vw, wb1, act, sumexp);
  k_tnet<<<32768 / 4, 256, 0, stream>>>(Ut, Vt, tb1, tW2, tb2, shlp, relp);

  k_gemm256<<<(MPAD / 256) * (VV / 256), 512, 0, stream>>>(act, wW2T, wb2, sumexp, MPAD / 256, VV / 256);

  k_toklogit<<<MROWS / 4, 256, 0, stream>>>(act, wW2T, wb2, sent, tokl);
  k_wp<<<32768 / 256, 256, 0, stream>>>(shlp, tokl, sumexp, wpb);
  k_dp<<<8, 1024, 0, stream>>>(wpb, relp, tokl, sumexp, finals);
  k_final<<<1, 64, 0, stream>>>(finals, out);
}